// Round 7
// baseline (275.076 us; speedup 1.0000x reference)
//
#include <hip/hip_runtime.h>

#define BB 4
#define CC 128
#define HH 180
#define WWW 180
#define HWHW (HH*WWW)       // 32400
#define CCAMD 256
#define NHEADS 4
#define HDD 128
#define NT 20000
#define MTOT 80000          // B*N, = 625 * 128 exactly
#define GAMMA_C 0.08f
#define EPS_C 1e-6f
#define SCALE_C 0.17677669529663687f  // 1/sqrt(32)

typedef short bf16x8 __attribute__((ext_vector_type(8)));
typedef float f32x4 __attribute__((ext_vector_type(4)));

static __device__ __forceinline__ unsigned short f2bf(float x) {
  unsigned int b = __float_as_uint(x);
  unsigned int r = (b + 0x7fffu + ((b >> 16) & 1u)) >> 16;
  return (unsigned short)r;
}
static __device__ __forceinline__ float b2f(unsigned short u) {
  return __uint_as_float(((unsigned int)u) << 16);
}

static __device__ __forceinline__ float warpMax(float v) {
#pragma unroll
  for (int o = 32; o >= 1; o >>= 1) v = fmaxf(v, __shfl_xor(v, o));
  return v;
}
static __device__ __forceinline__ float warpSum(float v) {
#pragma unroll
  for (int o = 32; o >= 1; o >>= 1) v += __shfl_xor(v, o);
  return v;
}

// ---------------------------------------------------------------------------
// k_prep_pix: blocks 0..95: weight f32->bf16; blocks 96..408: pixel indices.
// ---------------------------------------------------------------------------
__global__ __launch_bounds__(256) void k_prep_pix(
    const float* __restrict__ kw, const float* __restrict__ vw,
    const float* __restrict__ qw, const float* __restrict__ ow,
    unsigned short* __restrict__ kvw, unsigned short* __restrict__ qwb,
    unsigned short* __restrict__ owb, const int* __restrict__ cidx,
    int* __restrict__ pix_ws, float* __restrict__ hits)
{
  if (blockIdx.x < 96) {
    const int t = blockIdx.x * 256 + threadIdx.x;  // one float4 per thread
    float4 f;
    unsigned short* dst;
    if (t < 16384) {           // kv: 65536 elems
      f = (t < 8192) ? ((const float4*)kw)[t] : ((const float4*)vw)[t - 8192];
      dst = kvw + (size_t)t * 4;
    } else if (t < 20480) {    // q: 16384 elems
      const int i = t - 16384;
      f = ((const float4*)qw)[i];
      dst = qwb + (size_t)i * 4;
    } else {                   // out: 16384 elems
      const int i = t - 20480;
      f = ((const float4*)ow)[i];
      dst = owb + (size_t)i * 4;
    }
    ushort4 u;
    u.x = f2bf(f.x); u.y = f2bf(f.y); u.z = f2bf(f.z); u.w = f2bf(f.w);
    *(ushort4*)dst = u;
  } else {
    const int t = (blockIdx.x - 96) * 256 + threadIdx.x;
    if (t >= MTOT) return;
    const int2 ij = *(const int2*)(cidx + (size_t)t * 2);
    int ii = ij.x; ii = ii < 0 ? 0 : (ii > HH - 1 ? HH - 1 : ii);
    int jj = ij.y; jj = jj < 0 ? 0 : (jj > WWW - 1 ? WWW - 1 : jj);
    const int pix = ii * WWW + jj;
    pix_ws[t] = pix;
    atomicAdd(hits + (size_t)(t / NT) * HWHW + pix, 1.0f);
  }
}

// ---------------------------------------------------------------------------
// k_tr2: lidar_t[b][p][c] (bf16) = lidar[b][c][p].
// ---------------------------------------------------------------------------
__global__ __launch_bounds__(256) void k_tr2(
    const float* __restrict__ lidar, unsigned short* __restrict__ lidar_t)
{
  const int b = blockIdx.y;
  const int p = blockIdx.x * 256 + threadIdx.x;
  if (p >= HWHW) return;
  const int z = blockIdx.z;  // channel half
  const float* src = lidar + ((size_t)b * CC + z * 64) * HWHW + p;
  unsigned short* dst = lidar_t + ((size_t)b * HWHW + p) * 128 + z * 64;
#pragma unroll
  for (int c8 = 0; c8 < 8; ++c8) {
    bf16x8 v;
#pragma unroll
    for (int e = 0; e < 8; ++e)
      v[e] = (short)f2bf(src[(size_t)(c8 * 8 + e) * HWHW]);
    ((bf16x8*)dst)[c8] = v;
  }
}

// ---------------------------------------------------------------------------
// k_gemm (LDS-free): C[M=80000, NOUT] = A[M,K] * W[NOUT,K]^T  (MFMA 16x16x32)
// 4 waves, wave w owns rows [128*mblk + 32w, +32); per wave 32x128 output
// (acc[2][8]); all A/B fragments loaded DIRECTLY from global (no LDS tile,
// no barriers in the K-loop). B weights (<=128KB) are L2-resident; A rows
// are lane-exclusive so HBM traffic is read-once.
// AMODE 0: A f32 rows (tokens), cvt in regs.
// AMODE 2: A bf16 rows gathered from lidar_t via pixw.
// AMODE 3: A = V-half of kvb * softmax(logit)*gate computed on the fly.
// EPI 0: store bf16 rows (+opt bias). EPI 1: atomic f32 scatter into
// delta[B][HW][128] + column sums -> meanr. EPI 2: per-head logits vs kvb.
// ---------------------------------------------------------------------------
template<int KSTEPS, int KW, int AMODE, int EPI, int NOUT>
__global__ __launch_bounds__(256) void k_gemm(
    const float* __restrict__ Af32, const unsigned short* __restrict__ Abf,
    const unsigned short* __restrict__ Bw, const float* __restrict__ bias,
    unsigned short* __restrict__ Dbf, const int* __restrict__ pixw,
    float* __restrict__ aux,            // EPI1: delta; EPI2: logits out
    const unsigned short* __restrict__ kvb, float* __restrict__ meanr,
    const float* __restrict__ smMp, const float* __restrict__ smSinvp,
    const float* __restrict__ gatep, const float* __restrict__ logp)
{
  __shared__ float scratch[512];
  const int tid = threadIdx.x;
  const int lane = tid & 63, wave = tid >> 6;
  const int l16 = lane & 15, kg = lane >> 4;
  const int mblk = blockIdx.x, nblk = blockIdx.y;
  const int rb = mblk * 128 + wave * 32;

  f32x4 acc[2][8];
#pragma unroll
  for (int i = 0; i < 2; ++i)
#pragma unroll
    for (int j = 0; j < 8; ++j) acc[i][j] = (f32x4)0.0f;

  // per-mf A row pointers / params (row = rb + mf*16 + l16)
  const float* a32p[2];
  const unsigned short* abfp[2];
  float ga[2];
  int lb[2], bbm[2];
#pragma unroll
  for (int mf = 0; mf < 2; ++mf) {
    const int ar = rb + mf * 16 + l16;
    if constexpr (AMODE == 0) {
      a32p[mf] = Af32 + (size_t)ar * KW;
    } else if constexpr (AMODE == 2) {
      const int bb = ar / NT;
      const int pix = pixw[ar];
      abfp[mf] = Abf + ((size_t)bb * HWHW + pix) * 128;
    } else {  // AMODE 3
      const int bb = ar / NT, n = ar - bb * NT;
      abfp[mf] = kvb + (size_t)ar * 256 + 128;
      ga[mf] = gatep[(size_t)bb * NT + n];
      lb[mf] = bb * NHEADS * NT + n;
      bbm[mf] = bb;
    }
  }
  // per-nf B row pointers (row = nblk*128 + nf*16 + l16)
  const unsigned short* bp[8];
#pragma unroll
  for (int nf = 0; nf < 8; ++nf)
    bp[nf] = Bw + (size_t)(nblk * 128 + nf * 16 + l16) * KW;

#pragma unroll
  for (int kt = 0; kt < KSTEPS; ++kt) {
#pragma unroll
    for (int ks = 0; ks < 2; ++ks) {
      const int c0 = kt * 64 + ks * 32 + kg * 8;
      bf16x8 a[2];
      if constexpr (AMODE == 0) {
#pragma unroll
        for (int mf = 0; mf < 2; ++mf) {
          const float4 f0 = *(const float4*)(a32p[mf] + c0);
          const float4 f1 = *(const float4*)(a32p[mf] + c0 + 4);
          bf16x8 v;
          v[0] = (short)f2bf(f0.x); v[1] = (short)f2bf(f0.y);
          v[2] = (short)f2bf(f0.z); v[3] = (short)f2bf(f0.w);
          v[4] = (short)f2bf(f1.x); v[5] = (short)f2bf(f1.y);
          v[6] = (short)f2bf(f1.z); v[7] = (short)f2bf(f1.w);
          a[mf] = v;
        }
      } else if constexpr (AMODE == 2) {
#pragma unroll
        for (int mf = 0; mf < 2; ++mf)
          a[mf] = *(const bf16x8*)(abfp[mf] + c0);
      } else {  // AMODE 3
        const int h = kt * 2 + ks;
#pragma unroll
        for (int mf = 0; mf < 2; ++mf) {
          const int bh = bbm[mf] * NHEADS + h;
          const float coef =
              __expf(logp[lb[mf] + h * NT] - smMp[bh]) * smSinvp[bh] * ga[mf];
          const bf16x8 v = *(const bf16x8*)(abfp[mf] + c0);
          bf16x8 o;
#pragma unroll
          for (int e = 0; e < 8; ++e)
            o[e] = (short)f2bf(b2f((unsigned short)v[e]) * coef);
          a[mf] = o;
        }
      }
      bf16x8 b[8];
#pragma unroll
      for (int nf = 0; nf < 8; ++nf)
        b[nf] = *(const bf16x8*)(bp[nf] + c0);
#pragma unroll
      for (int mf = 0; mf < 2; ++mf)
#pragma unroll
        for (int nf = 0; nf < 8; ++nf)
          acc[mf][nf] =
              __builtin_amdgcn_mfma_f32_16x16x32_bf16(a[mf], b[nf], acc[mf][nf], 0, 0, 0);
    }
  }

  // ---- epilogue ----
  if constexpr (EPI == 0) {
    float bv[8];
#pragma unroll
    for (int nf = 0; nf < 8; ++nf)
      bv[nf] = bias ? bias[nblk * 128 + nf * 16 + l16] : 0.0f;
#pragma unroll
    for (int mf = 0; mf < 2; ++mf) {
#pragma unroll
      for (int j = 0; j < 4; ++j) {
        const int row = rb + mf * 16 + kg * 4 + j;
        unsigned short* dr = Dbf + (size_t)row * NOUT + nblk * 128 + l16;
#pragma unroll
        for (int nf = 0; nf < 8; ++nf)
          dr[nf * 16] = f2bf(acc[mf][nf][j] + bv[nf]);
      }
    }
  } else if constexpr (EPI == 1) {
    // scatter + block column sums
    scratch[tid] = 0.0f;
    scratch[256 + tid] = 0.0f;
    __syncthreads();
    const int b0 = (mblk * 128) / NT;
#pragma unroll
    for (int mf = 0; mf < 2; ++mf) {
      const int baser = rb + mf * 16 + kg * 4;
      const int bb = baser / NT;          // uniform over j (NT % 4 == 0)
      const int bsel = (bb != b0) ? 1 : 0;
      float s[8] = {0, 0, 0, 0, 0, 0, 0, 0};
#pragma unroll
      for (int j = 0; j < 4; ++j) {
        const int row = baser + j;
        const int pix = pixw[row];
        float* dr = aux + ((size_t)bb * HWHW + pix) * 128 + l16;
#pragma unroll
        for (int nf = 0; nf < 8; ++nf) {
          atomicAdd(dr + nf * 16, acc[mf][nf][j]);
          s[nf] += acc[mf][nf][j];
        }
      }
#pragma unroll
      for (int nf = 0; nf < 8; ++nf)
        atomicAdd(&scratch[bsel * 128 + nf * 16 + l16], s[nf]);
    }
    __syncthreads();
    const int b1 = (mblk * 128 + 127) / NT;
    if (tid < 128) atomicAdd(meanr + (size_t)b0 * 128 + tid, scratch[tid]);
    else if (b1 != b0) atomicAdd(meanr + (size_t)b1 * 128 + (tid - 128), scratch[tid]);
  } else {
    // EPI 2: per-head logits vs K-half of kvb; reduce over l16 group.
    float bv[8];
#pragma unroll
    for (int nf = 0; nf < 8; ++nf) bv[nf] = bias[nf * 16 + l16];
#pragma unroll
    for (int mf = 0; mf < 2; ++mf) {
#pragma unroll
      for (int j = 0; j < 4; ++j) {
        const int rl = wave * 32 + mf * 16 + kg * 4 + j;
        const int row = mblk * 128 + rl;
        const unsigned short* kr = kvb + (size_t)row * 256 + l16;
        float s[4];
#pragma unroll
        for (int h = 0; h < 4; ++h)
          s[h] = (acc[mf][2 * h][j] + bv[2 * h]) * b2f(kr[2 * h * 16]) +
                 (acc[mf][2 * h + 1][j] + bv[2 * h + 1]) * b2f(kr[(2 * h + 1) * 16]);
#pragma unroll
        for (int h = 0; h < 4; ++h) {
          s[h] += __shfl_xor(s[h], 8, 16);
          s[h] += __shfl_xor(s[h], 4, 16);
          s[h] += __shfl_xor(s[h], 2, 16);
          s[h] += __shfl_xor(s[h], 1, 16);
        }
        if (l16 == 0) {
#pragma unroll
          for (int h = 0; h < 4; ++h) scratch[rl * 4 + h] = s[h];
        }
      }
    }
    __syncthreads();
    if (tid < 128) {
      const int row = mblk * 128 + tid;
      const int bb = row / NT, n = row - bb * NT;
#pragma unroll
      for (int h = 0; h < 4; ++h)
        aux[((size_t)bb * NHEADS + h) * NT + n] = scratch[tid * 4 + h] * SCALE_C;
    }
  }
}

// ---------------------------------------------------------------------------
// k_smpart: per-(bh, chunk) partial max & sum-exp.  NT = 8 * 2500.
// ---------------------------------------------------------------------------
__global__ __launch_bounds__(256) void k_smpart(
    const float* __restrict__ logits, float* __restrict__ pm,
    float* __restrict__ ps)
{
  const int ch = blockIdx.x, bh = blockIdx.y;
  const float* L = logits + (size_t)bh * NT + ch * 2500;
  const int tid = threadIdx.x;
  __shared__ float sred[4];

  float m = -INFINITY;
  for (int i = tid; i < 2500; i += 256) m = fmaxf(m, L[i]);
  m = warpMax(m);
  if ((tid & 63) == 0) sred[tid >> 6] = m;
  __syncthreads();
  m = fmaxf(fmaxf(sred[0], sred[1]), fmaxf(sred[2], sred[3]));

  float s = 0.0f;
  for (int i = tid; i < 2500; i += 256) s += __expf(L[i] - m);
  s = warpSum(s);
  __syncthreads();
  if ((tid & 63) == 0) sred[tid >> 6] = s;
  __syncthreads();
  if (tid == 0) {
    pm[bh * 8 + ch] = m;
    ps[bh * 8 + ch] = sred[0] + sred[1] + sred[2] + sred[3];
  }
}

// ---------------------------------------------------------------------------
// k_cntfix: block b: cnt[b] = #hit pixels. Block 0 also combines softmax
// partials -> smM, smSinv.
// ---------------------------------------------------------------------------
__global__ __launch_bounds__(256) void k_cntfix(
    const float* __restrict__ hits, float* __restrict__ cnt,
    const float* __restrict__ pm, const float* __restrict__ ps,
    float* __restrict__ smM, float* __restrict__ smSinv)
{
  const int b = blockIdx.x;
  const int tid = threadIdx.x;
  float s = 0.0f;
  for (int i = tid; i < HWHW; i += 256)
    s += (hits[(size_t)b * HWHW + i] > 0.0f) ? 1.0f : 0.0f;
  s = warpSum(s);
  __shared__ float sred[4];
  if ((tid & 63) == 0) sred[tid >> 6] = s;
  __syncthreads();
  if (tid == 0) cnt[b] = sred[0] + sred[1] + sred[2] + sred[3];
  if (b == 0 && tid < BB * NHEADS) {
    float M = -INFINITY;
#pragma unroll
    for (int c = 0; c < 8; ++c) M = fmaxf(M, pm[tid * 8 + c]);
    float S = 0.0f;
#pragma unroll
    for (int c = 0; c < 8; ++c) S += ps[tid * 8 + c] * __expf(pm[tid * 8 + c] - M);
    smM[tid] = M;
    smSinv[tid] = 1.0f / S;
  }
}

// ---------------------------------------------------------------------------
// k_final: out[b][c][hw] = lidar + (delta[b][hw][c] - mean*mask)*alpha*gamma
// 80px x 128ch tiles, 512 threads; hits-gated delta reads; XOR-swizzled LDS.
// ---------------------------------------------------------------------------
__global__ __launch_bounds__(512) void k_final(
    const float* __restrict__ lidar, const float* __restrict__ alpha,
    const float* __restrict__ hits, const float* __restrict__ mean_raw,
    const float* __restrict__ cnt, const float* __restrict__ delta,
    float* __restrict__ out)
{
  __shared__ float tile[80 * 136];
  const int b = blockIdx.y;
  const int p0 = blockIdx.x * 80;
  const int t = threadIdx.x;
  const float4* dsrc = (const float4*)(delta + ((size_t)b * HWHW + p0) * 128);
  const float* hrow = hits + (size_t)b * HWHW + p0;
#pragma unroll
  for (int i = 0; i < 5; ++i) {
    const int idx4 = i * 512 + t;         // 2560 float4 = 80px * 32
    const int p = idx4 >> 5, c4 = idx4 & 31;
    float4 f = make_float4(0.0f, 0.0f, 0.0f, 0.0f);
    if (hrow[p] > 0.0f) f = dsrc[idx4];
    *(float4*)&tile[p * 136 + ((c4 ^ (p & 7)) << 2)] = f;
  }
  __syncthreads();
  const int c = t >> 2, sub = t & 3;
  const int cq = c >> 2, cr = c & 3;
  const float mn = mean_raw[b * 128 + c] / (cnt[b] + EPS_C);
  const size_t cbase = ((size_t)b * CC + c) * HWHW + p0;
  const size_t hbase = (size_t)b * HWHW + p0;
#pragma unroll
  for (int j = 0; j < 5; ++j) {
    const int pq = j * 16 + sub * 4;
    float4 d;
    d.x = tile[(pq + 0) * 136 + (((cq ^ ((pq + 0) & 7)) << 2) | cr)];
    d.y = tile[(pq + 1) * 136 + (((cq ^ ((pq + 1) & 7)) << 2) | cr)];
    d.z = tile[(pq + 2) * 136 + (((cq ^ ((pq + 2) & 7)) << 2) | cr)];
    d.w = tile[(pq + 3) * 136 + (((cq ^ ((pq + 3) & 7)) << 2) | cr)];
    const float4 li = *(const float4*)(lidar + cbase + pq);
    const float4 al = *(const float4*)(alpha + p0 + pq);
    const float4 ht = *(const float4*)(hits + hbase + pq);
    float4 o;
    o.x = li.x + (d.x - (ht.x > 0.0f ? mn : 0.0f)) * al.x * GAMMA_C;
    o.y = li.y + (d.y - (ht.y > 0.0f ? mn : 0.0f)) * al.y * GAMMA_C;
    o.z = li.z + (d.z - (ht.z > 0.0f ? mn : 0.0f)) * al.z * GAMMA_C;
    o.w = li.w + (d.w - (ht.w > 0.0f ? mn : 0.0f)) * al.w * GAMMA_C;
    *(float4*)(out + cbase + pq) = o;
  }
}

// ---------------------------------------------------------------------------
extern "C" void kernel_launch(void* const* d_in, const int* in_sizes, int n_in,
                              void* d_out, int out_size, void* d_ws, size_t ws_size,
                              hipStream_t stream)
{
  const float* lidar  = (const float*)d_in[0];
  const float* tokens = (const float*)d_in[1];
  const float* gate   = (const float*)d_in[2];
  const float* alpha  = (const float*)d_in[3];
  const float* q_w    = (const float*)d_in[4];
  const float* q_b    = (const float*)d_in[5];
  const float* k_w    = (const float*)d_in[6];
  const float* v_w    = (const float*)d_in[7];
  const float* out_w  = (const float*)d_in[8];
  const int*   cidx   = (const int*)d_in[9];
  float* out = (float*)d_out;

  char* W = (char*)d_ws;
  // kv_bf [80000][256] bf16
  unsigned short* kv_bf = (unsigned short*)(W + 0);                 // 40,960,000
  // delta [B][HW][128] f32 (66,355,200). Until its memset this region also
  // hosts lidar_t (at +20,480,000 within; 33,177,600) — dead before memset.
  float* delta = (float*)(W + 61440000);
  unsigned short* lidar_t = (unsigned short*)(W + 81920000);
  float* logits   = (float*)(W + 127795200);   // 1,280,000
  int*   pix_ws   = (int*)(W + 129075200);     //   320,000
  float* hits     = (float*)(W + 129395200);   //   518,400
  float* mean_raw = (float*)(W + 129913600);   //     2,048
  float* cnt      = (float*)(W + 129915648);   //        64
  unsigned short* kvw_bf = (unsigned short*)(W + 129915712);  // 131,072
  unsigned short* qw_bf  = (unsigned short*)(W + 130046784);  //  32,768
  unsigned short* ow_bf  = (unsigned short*)(W + 130079552);  //  32,768
  float* pm     = (float*)(W + 130112320);     // 512
  float* ps     = (float*)(W + 130112832);     // 512
  float* smM    = (float*)(W + 130113344);     // 64
  float* smSinv = (float*)(W + 130113408);     // 64

  hipMemsetAsync(hits, 0, (size_t)BB * HWHW * sizeof(float), stream);
  hipMemsetAsync(mean_raw, 0, 2048 + 64, stream);

  k_prep_pix<<<dim3(409), 256, 0, stream>>>(k_w, v_w, q_w, out_w, kvw_bf,
                                            qw_bf, ow_bf, cidx, pix_ws, hits);
  k_tr2<<<dim3(127, BB, 2), 256, 0, stream>>>(lidar, lidar_t);
  // kv projection: [80000,256] x [256,256]^T   (nblk 0 = K rows, 1 = V rows)
  k_gemm<4, 256, 0, 0, 256><<<dim3(625, 2), 256, 0, stream>>>(
      tokens, nullptr, kvw_bf, nullptr, kv_bf, nullptr, nullptr, nullptr,
      nullptr, nullptr, nullptr, nullptr, nullptr);
  // q projection (rows gathered from lidar_t) -> per-head logits directly
  k_gemm<2, 128, 2, 2, 128><<<dim3(625, 1), 256, 0, stream>>>(
      nullptr, lidar_t, qw_bf, q_b, nullptr, pix_ws, logits, kv_bf,
      nullptr, nullptr, nullptr, nullptr, nullptr);
  // lidar_t dead from here
  hipMemsetAsync(delta, 0, (size_t)BB * HWHW * 128 * sizeof(float), stream);
  k_smpart<<<dim3(8, BB * NHEADS), 256, 0, stream>>>(logits, pm, ps);
  k_cntfix<<<dim3(BB), 256, 0, stream>>>(hits, cnt, pm, ps, smM, smSinv);
  // out projection with fused attention-weighted V + scatter + mean accum
  k_gemm<2, 128, 3, 1, 128><<<dim3(625, 1), 256, 0, stream>>>(
      nullptr, nullptr, ow_bf, nullptr, nullptr, pix_ws, delta, kv_bf,
      mean_raw, smM, smSinv, gate, logits);
  k_final<<<dim3(405, BB), 512, 0, stream>>>(lidar, alpha, hits, mean_raw, cnt,
                                             delta, out);
}

// Round 8
// 234.982 us; speedup vs baseline: 1.1706x; 1.1706x over previous
//
#include <hip/hip_runtime.h>

#define BB 4
#define CC 128
#define HH 180
#define WWW 180
#define HWHW (HH*WWW)       // 32400
#define CCAMD 256
#define NHEADS 4
#define HDD 128
#define NT 20000
#define MTOT 80000          // B*N, = 625 * 128 exactly
#define GAMMA_C 0.08f
#define EPS_C 1e-6f
#define SCALE_C 0.17677669529663687f  // 1/sqrt(32)

typedef short bf16x8 __attribute__((ext_vector_type(8)));
typedef float f32x4 __attribute__((ext_vector_type(4)));

typedef __attribute__((address_space(1))) const unsigned int GU;
typedef __attribute__((address_space(3))) unsigned int LU;

static __device__ __forceinline__ void gll16(const void* g, void* l) {
  __builtin_amdgcn_global_load_lds((GU*)g, (LU*)l, 16, 0, 0);
}

static __device__ __forceinline__ unsigned short f2bf(float x) {
  unsigned int b = __float_as_uint(x);
  unsigned int r = (b + 0x7fffu + ((b >> 16) & 1u)) >> 16;
  return (unsigned short)r;
}
static __device__ __forceinline__ float b2f(unsigned short u) {
  return __uint_as_float(((unsigned int)u) << 16);
}

static __device__ __forceinline__ float warpMax(float v) {
#pragma unroll
  for (int o = 32; o >= 1; o >>= 1) v = fmaxf(v, __shfl_xor(v, o));
  return v;
}
static __device__ __forceinline__ float warpSum(float v) {
#pragma unroll
  for (int o = 32; o >= 1; o >>= 1) v += __shfl_xor(v, o);
  return v;
}

// ---------------------------------------------------------------------------
// k_prep_pix: blocks 0..95: weight f32->bf16; blocks 96..408: pixel indices.
// ---------------------------------------------------------------------------
__global__ __launch_bounds__(256) void k_prep_pix(
    const float* __restrict__ kw, const float* __restrict__ vw,
    const float* __restrict__ qw, const float* __restrict__ ow,
    unsigned short* __restrict__ kvw, unsigned short* __restrict__ qwb,
    unsigned short* __restrict__ owb, const int* __restrict__ cidx,
    int* __restrict__ pix_ws, float* __restrict__ hits)
{
  if (blockIdx.x < 96) {
    const int t = blockIdx.x * 256 + threadIdx.x;  // one float4 per thread
    float4 f;
    unsigned short* dst;
    if (t < 16384) {           // kv: 65536 elems
      f = (t < 8192) ? ((const float4*)kw)[t] : ((const float4*)vw)[t - 8192];
      dst = kvw + (size_t)t * 4;
    } else if (t < 20480) {    // q: 16384 elems
      const int i = t - 16384;
      f = ((const float4*)qw)[i];
      dst = qwb + (size_t)i * 4;
    } else {                   // out: 16384 elems
      const int i = t - 20480;
      f = ((const float4*)ow)[i];
      dst = owb + (size_t)i * 4;
    }
    ushort4 u;
    u.x = f2bf(f.x); u.y = f2bf(f.y); u.z = f2bf(f.z); u.w = f2bf(f.w);
    *(ushort4*)dst = u;
  } else {
    const int t = (blockIdx.x - 96) * 256 + threadIdx.x;
    if (t >= MTOT) return;
    const int2 ij = *(const int2*)(cidx + (size_t)t * 2);
    int ii = ij.x; ii = ii < 0 ? 0 : (ii > HH - 1 ? HH - 1 : ii);
    int jj = ij.y; jj = jj < 0 ? 0 : (jj > WWW - 1 ? WWW - 1 : jj);
    const int pix = ii * WWW + jj;
    pix_ws[t] = pix;
    atomicAdd(hits + (size_t)(t / NT) * HWHW + pix, 1.0f);
  }
}

// ---------------------------------------------------------------------------
// k_tr2: lidar_t[b][p][c] (bf16) = lidar[b][c][p].
// ---------------------------------------------------------------------------
__global__ __launch_bounds__(256) void k_tr2(
    const float* __restrict__ lidar, unsigned short* __restrict__ lidar_t)
{
  const int b = blockIdx.y;
  const int p = blockIdx.x * 256 + threadIdx.x;
  if (p >= HWHW) return;
  const int z = blockIdx.z;  // channel half
  const float* src = lidar + ((size_t)b * CC + z * 64) * HWHW + p;
  unsigned short* dst = lidar_t + ((size_t)b * HWHW + p) * 128 + z * 64;
#pragma unroll
  for (int c8 = 0; c8 < 8; ++c8) {
    bf16x8 v;
#pragma unroll
    for (int e = 0; e < 8; ++e)
      v[e] = (short)f2bf(src[(size_t)(c8 * 8 + e) * HWHW]);
    ((bf16x8*)dst)[c8] = v;
  }
}

// ---------------------------------------------------------------------------
// k_gemm: C[M=80000, NOUT] = A[M,K] * W[NOUT,K]^T   (bf16 MFMA 16x16x32)
// BM=BN=128, BK=64, 4 waves 2x2, each wave 64x64 (4x4 fragments).
// DOUBLE-BUFFERED 2-phase pipeline (T3 minimum): STAGE(t+1) issued BEFORE
// compute(t); reg-staged A modes use the T14 split (global loads pre-compute,
// ds_write post-compute); one vmcnt(0)+barrier per K-tile.
// AMODE 0: A f32 reg-staged+cvt. AMODE 1: A bf16 rows via gll16.
// AMODE 2: A bf16 rows gathered from lidar_t via pixw.
// AMODE 3: A = V-half of kvb * softmax(logit)*gate (reg-staged).
// LDS XOR-swizzled on the source side; matching swizzle on ds_read.
// EPI 0: store bf16 rows (+opt bias).
// EPI 1: atomic f32 scatter into delta[B][HW][128] + column sums -> meanr.
// EPI 2: per-head logits vs K-half of kvb.
// ---------------------------------------------------------------------------
template<int KSTEPS, int KW, int AMODE, int EPI, int NOUT>
__global__ __launch_bounds__(256) void k_gemm(
    const float* __restrict__ Af32, const unsigned short* __restrict__ Abf,
    const unsigned short* __restrict__ Bw, const float* __restrict__ bias,
    unsigned short* __restrict__ Dbf, const int* __restrict__ pixw,
    float* __restrict__ aux,            // EPI1: delta; EPI2: logits out
    const unsigned short* __restrict__ kvb, float* __restrict__ meanr,
    const float* __restrict__ smMp, const float* __restrict__ smSinvp,
    const float* __restrict__ gatep, const float* __restrict__ logp)
{
  __shared__ unsigned short lds[2][16384];  // per buf: A [0,8192), B [8192,16384)
  const int tid = threadIdx.x;
  const int lane = tid & 63, wave = tid >> 6;
  const int wm = wave >> 1, wn = wave & 1;
  const int mblk = blockIdx.x, nblk = blockIdx.y;
  const int l16 = lane & 15, kg = lane >> 4;

  const int g3 = lane >> 3;        // row within 8-row group (== lds_row & 7)
  const int c8l = lane & 7;
  const int grow0 = wave * 8 + g3;
  const int gcol_lin = c8l * 8;
  const int gcol_swz = (c8l ^ g3) * 8;

  f32x4 acc[4][4];
#pragma unroll
  for (int i = 0; i < 4; ++i)
#pragma unroll
    for (int j = 0; j < 4; ++j) acc[i][j] = (f32x4)0.0f;

  // per-w2 A pointers / params
  const float* a32p[4];
  const unsigned short* arow[4];
  const unsigned short* vrow[4];
  float ga4[4];
  int lbase[4], rb4[4];
  if constexpr (AMODE == 0) {
#pragma unroll
    for (int w2 = 0; w2 < 4; ++w2)
      a32p[w2] = Af32 + (size_t)(mblk * 128 + w2 * 32 + grow0) * KW + gcol_lin;
  } else if constexpr (AMODE == 2) {
#pragma unroll
    for (int w2 = 0; w2 < 4; ++w2) {
      const int r = mblk * 128 + w2 * 32 + grow0;
      const int bb = r / NT;
      const int pix = pixw[r];
      arow[w2] = Abf + ((size_t)bb * HWHW + pix) * 128 + gcol_swz;
    }
  } else if constexpr (AMODE == 3) {
#pragma unroll
    for (int w2 = 0; w2 < 4; ++w2) {
      const int r = mblk * 128 + w2 * 32 + grow0;
      const int bb = r / NT, n = r - bb * NT;
      vrow[w2] = kvb + (size_t)r * 256 + 128 + gcol_lin;
      ga4[w2] = gatep[(size_t)bb * NT + n];
      lbase[w2] = bb * NHEADS * NT + n;
      rb4[w2] = bb;
    }
  }

  bf16x8 areg[4];  // in-flight A fragments for reg-staged modes

  auto loadA = [&](int kt) {  // AMODE 0 / 3: global -> areg (issue early)
    if constexpr (AMODE == 0) {
#pragma unroll
      for (int w2 = 0; w2 < 4; ++w2) {
        const float* g = a32p[w2] + kt * 64;
        const float4 f0 = *(const float4*)g;
        const float4 f1 = *(const float4*)(g + 4);
        bf16x8 v;
        v[0] = (short)f2bf(f0.x); v[1] = (short)f2bf(f0.y);
        v[2] = (short)f2bf(f0.z); v[3] = (short)f2bf(f0.w);
        v[4] = (short)f2bf(f1.x); v[5] = (short)f2bf(f1.y);
        v[6] = (short)f2bf(f1.z); v[7] = (short)f2bf(f1.w);
        areg[w2] = v;
      }
    } else if constexpr (AMODE == 3) {
      const int h = kt * 2 + (c8l >> 2);
#pragma unroll
      for (int w2 = 0; w2 < 4; ++w2) {
        const int bh = rb4[w2] * NHEADS + h;
        const float coef =
            __expf(logp[lbase[w2] + h * NT] - smMp[bh]) * smSinvp[bh] * ga4[w2];
        const bf16x8 v = *(const bf16x8*)(vrow[w2] + kt * 64);
        bf16x8 o;
#pragma unroll
        for (int e = 0; e < 8; ++e)
          o[e] = (short)f2bf(b2f((unsigned short)v[e]) * coef);
        areg[w2] = o;
      }
    }
  };
  auto writeA = [&](int nb) {  // areg -> LDS (after compute)
#pragma unroll
    for (int w2 = 0; w2 < 4; ++w2)
      *(bf16x8*)&lds[nb][w2 * 2048 + wave * 512 + g3 * 64 + gcol_swz] = areg[w2];
  };
  auto stageAg = [&](int kt, int nb) {  // AMODE 1 / 2: gll16 direct
    if constexpr (AMODE == 1) {
#pragma unroll
      for (int w2 = 0; w2 < 4; ++w2) {
        const unsigned short* g =
            Abf + (size_t)(mblk * 128 + w2 * 32 + grow0) * KW + kt * 64 + gcol_swz;
        gll16(g, &lds[nb][w2 * 2048 + wave * 512]);
      }
    } else if constexpr (AMODE == 2) {
#pragma unroll
      for (int w2 = 0; w2 < 4; ++w2)
        gll16(arow[w2] + kt * 64, &lds[nb][w2 * 2048 + wave * 512]);
    }
  };
  auto stageB = [&](int kt, int nb) {
#pragma unroll
    for (int w2 = 0; w2 < 4; ++w2) {
      const unsigned short* g =
          Bw + (size_t)(nblk * 128 + w2 * 32 + grow0) * KW + kt * 64 + gcol_swz;
      gll16(g, &lds[nb][8192 + w2 * 2048 + wave * 512]);
    }
  };
  auto compute = [&](int cb) {
#pragma unroll
    for (int ks = 0; ks < 2; ++ks) {
      const int swz = ((ks * 4 + kg) ^ (l16 & 7)) * 8;
      bf16x8 a[4], b[4];
#pragma unroll
      for (int mf = 0; mf < 4; ++mf)
        a[mf] = *(const bf16x8*)&lds[cb][(wm * 64 + mf * 16 + l16) * 64 + swz];
#pragma unroll
      for (int nf = 0; nf < 4; ++nf)
        b[nf] = *(const bf16x8*)&lds[cb][8192 + (wn * 64 + nf * 16 + l16) * 64 + swz];
#pragma unroll
      for (int mf = 0; mf < 4; ++mf)
#pragma unroll
        for (int nf = 0; nf < 4; ++nf)
          acc[mf][nf] =
              __builtin_amdgcn_mfma_f32_16x16x32_bf16(a[mf], b[nf], acc[mf][nf], 0, 0, 0);
    }
  };

  // ---- prologue: stage tile 0 into buf 0 ----
  if constexpr (AMODE == 0 || AMODE == 3) {
    loadA(0);
    writeA(0);
  } else {
    stageAg(0, 0);
  }
  stageB(0, 0);
  __syncthreads();

  // ---- 2-phase pipelined K-loop ----
  int cur = 0;
  for (int kt = 0; kt < KSTEPS; ++kt) {
    if (kt + 1 < KSTEPS) {
      if constexpr (AMODE == 0 || AMODE == 3) loadA(kt + 1);
      else stageAg(kt + 1, cur ^ 1);
      stageB(kt + 1, cur ^ 1);
    }
    compute(cur);
    if (kt + 1 < KSTEPS) {
      if constexpr (AMODE == 0 || AMODE == 3) writeA(cur ^ 1);
    }
    __syncthreads();
    cur ^= 1;
  }

  float* scratch = (float*)&lds[0][0];  // free after final barrier

  // ---- epilogue ----
  if constexpr (EPI == 0) {
    float bv[4];
#pragma unroll
    for (int nf = 0; nf < 4; ++nf) {
      const int colg = nblk * 128 + wn * 64 + nf * 16 + l16;
      bv[nf] = bias ? bias[colg] : 0.0f;
    }
#pragma unroll
    for (int mf = 0; mf < 4; ++mf) {
#pragma unroll
      for (int j = 0; j < 4; ++j) {
        const int row = mblk * 128 + wm * 64 + mf * 16 + kg * 4 + j;
        unsigned short* dr = Dbf + (size_t)row * NOUT + nblk * 128 + wn * 64 + l16;
#pragma unroll
        for (int nf = 0; nf < 4; ++nf)
          dr[nf * 16] = f2bf(acc[mf][nf][j] + bv[nf]);
      }
    }
  } else if constexpr (EPI == 1) {
    // scatter + block column sums
    scratch[tid] = 0.0f;
    __syncthreads();
    const int b0 = (mblk * 128) / NT;
#pragma unroll
    for (int mf = 0; mf < 4; ++mf) {
      const int baser = mblk * 128 + wm * 64 + mf * 16 + kg * 4;
      const int bb = baser / NT;          // uniform over j (NT % 4 == 0)
      const int bsel = (bb != b0) ? 1 : 0;
      float s[4] = {0.0f, 0.0f, 0.0f, 0.0f};
#pragma unroll
      for (int j = 0; j < 4; ++j) {
        const int row = baser + j;
        const int pix = pixw[row];
        float* dr = aux + ((size_t)bb * HWHW + pix) * 128 + wn * 64 + l16;
#pragma unroll
        for (int nf = 0; nf < 4; ++nf) {
          atomicAdd(dr + nf * 16, acc[mf][nf][j]);
          s[nf] += acc[mf][nf][j];
        }
      }
#pragma unroll
      for (int nf = 0; nf < 4; ++nf)
        atomicAdd(&scratch[bsel * 128 + wn * 64 + nf * 16 + l16], s[nf]);
    }
    __syncthreads();
    const int b1 = (mblk * 128 + 127) / NT;
    if (tid < 128) atomicAdd(meanr + (size_t)b0 * 128 + tid, scratch[tid]);
    else if (b1 != b0) atomicAdd(meanr + (size_t)b1 * 128 + (tid - 128), scratch[tid]);
  } else {
    // EPI 2: logits. head = wn*2 + (nf>>1); reduce over l16 group.
    float bv[4];
#pragma unroll
    for (int nf = 0; nf < 4; ++nf)
      bv[nf] = bias[wn * 64 + nf * 16 + l16];
#pragma unroll
    for (int mf = 0; mf < 4; ++mf) {
#pragma unroll
      for (int j = 0; j < 4; ++j) {
        const int rl = wm * 64 + mf * 16 + kg * 4 + j;
        const int row = mblk * 128 + rl;
        const unsigned short* kr = kvb + (size_t)row * 256 + wn * 64 + l16;
        float s0 = (acc[mf][0][j] + bv[0]) * b2f(kr[0]) +
                   (acc[mf][1][j] + bv[1]) * b2f(kr[16]);
        float s1 = (acc[mf][2][j] + bv[2]) * b2f(kr[32]) +
                   (acc[mf][3][j] + bv[3]) * b2f(kr[48]);
        s0 += __shfl_xor(s0, 8, 16); s0 += __shfl_xor(s0, 4, 16);
        s0 += __shfl_xor(s0, 2, 16); s0 += __shfl_xor(s0, 1, 16);
        s1 += __shfl_xor(s1, 8, 16); s1 += __shfl_xor(s1, 4, 16);
        s1 += __shfl_xor(s1, 2, 16); s1 += __shfl_xor(s1, 1, 16);
        if (l16 == 0) {
          scratch[rl * 4 + wn * 2 + 0] = s0;
          scratch[rl * 4 + wn * 2 + 1] = s1;
        }
      }
    }
    __syncthreads();
    if (tid < 128) {
      const int row = mblk * 128 + tid;
      const int bb = row / NT, n = row - bb * NT;
#pragma unroll
      for (int h = 0; h < 4; ++h)
        aux[((size_t)bb * NHEADS + h) * NT + n] = scratch[tid * 4 + h] * SCALE_C;
    }
  }
}

// ---------------------------------------------------------------------------
// k_smpart: per-(bh, chunk) partial max & sum-exp.  NT = 8 * 2500.
// ---------------------------------------------------------------------------
__global__ __launch_bounds__(256) void k_smpart(
    const float* __restrict__ logits, float* __restrict__ pm,
    float* __restrict__ ps)
{
  const int ch = blockIdx.x, bh = blockIdx.y;
  const float* L = logits + (size_t)bh * NT + ch * 2500;
  const int tid = threadIdx.x;
  __shared__ float sred[4];

  float m = -INFINITY;
  for (int i = tid; i < 2500; i += 256) m = fmaxf(m, L[i]);
  m = warpMax(m);
  if ((tid & 63) == 0) sred[tid >> 6] = m;
  __syncthreads();
  m = fmaxf(fmaxf(sred[0], sred[1]), fmaxf(sred[2], sred[3]));

  float s = 0.0f;
  for (int i = tid; i < 2500; i += 256) s += __expf(L[i] - m);
  s = warpSum(s);
  __syncthreads();
  if ((tid & 63) == 0) sred[tid >> 6] = s;
  __syncthreads();
  if (tid == 0) {
    pm[bh * 8 + ch] = m;
    ps[bh * 8 + ch] = sred[0] + sred[1] + sred[2] + sred[3];
  }
}

// ---------------------------------------------------------------------------
// k_cntfix: block b: cnt[b] = #hit pixels. Block 0 also combines softmax
// partials -> smM, smSinv.
// ---------------------------------------------------------------------------
__global__ __launch_bounds__(256) void k_cntfix(
    const float* __restrict__ hits, float* __restrict__ cnt,
    const float* __restrict__ pm, const float* __restrict__ ps,
    float* __restrict__ smM, float* __restrict__ smSinv)
{
  const int b = blockIdx.x;
  const int tid = threadIdx.x;
  float s = 0.0f;
  for (int i = tid; i < HWHW; i += 256)
    s += (hits[(size_t)b * HWHW + i] > 0.0f) ? 1.0f : 0.0f;
  s = warpSum(s);
  __shared__ float sred[4];
  if ((tid & 63) == 0) sred[tid >> 6] = s;
  __syncthreads();
  if (tid == 0) cnt[b] = sred[0] + sred[1] + sred[2] + sred[3];
  if (b == 0 && tid < BB * NHEADS) {
    float M = -INFINITY;
#pragma unroll
    for (int c = 0; c < 8; ++c) M = fmaxf(M, pm[tid * 8 + c]);
    float S = 0.0f;
#pragma unroll
    for (int c = 0; c < 8; ++c) S += ps[tid * 8 + c] * __expf(pm[tid * 8 + c] - M);
    smM[tid] = M;
    smSinv[tid] = 1.0f / S;
  }
}

// ---------------------------------------------------------------------------
// k_final: out[b][c][hw] = lidar + (delta[b][hw][c] - mean*mask)*alpha*gamma
// 80px x 128ch tiles, 512 threads; hits-gated delta reads; XOR-swizzled LDS.
// ---------------------------------------------------------------------------
__global__ __launch_bounds__(512) void k_final(
    const float* __restrict__ lidar, const float* __restrict__ alpha,
    const float* __restrict__ hits, const float* __restrict__ mean_raw,
    const float* __restrict__ cnt, const float* __restrict__ delta,
    float* __restrict__ out)
{
  __shared__ float tile[80 * 136];
  const int b = blockIdx.y;
  const int p0 = blockIdx.x * 80;
  const int t = threadIdx.x;
  const float4* dsrc = (const float4*)(delta + ((size_t)b * HWHW + p0) * 128);
  const float* hrow = hits + (size_t)b * HWHW + p0;
#pragma unroll
  for (int i = 0; i < 5; ++i) {
    const int idx4 = i * 512 + t;         // 2560 float4 = 80px * 32
    const int p = idx4 >> 5, c4 = idx4 & 31;
    float4 f = make_float4(0.0f, 0.0f, 0.0f, 0.0f);
    if (hrow[p] > 0.0f) f = dsrc[idx4];
    *(float4*)&tile[p * 136 + ((c4 ^ (p & 7)) << 2)] = f;
  }
  __syncthreads();
  const int c = t >> 2, sub = t & 3;
  const int cq = c >> 2, cr = c & 3;
  const float mn = mean_raw[b * 128 + c] / (cnt[b] + EPS_C);
  const size_t cbase = ((size_t)b * CC + c) * HWHW + p0;
  const size_t hbase = (size_t)b * HWHW + p0;
#pragma unroll
  for (int j = 0; j < 5; ++j) {
    const int pq = j * 16 + sub * 4;
    float4 d;
    d.x = tile[(pq + 0) * 136 + (((cq ^ ((pq + 0) & 7)) << 2) | cr)];
    d.y = tile[(pq + 1) * 136 + (((cq ^ ((pq + 1) & 7)) << 2) | cr)];
    d.z = tile[(pq + 2) * 136 + (((cq ^ ((pq + 2) & 7)) << 2) | cr)];
    d.w = tile[(pq + 3) * 136 + (((cq ^ ((pq + 3) & 7)) << 2) | cr)];
    const float4 li = *(const float4*)(lidar + cbase + pq);
    const float4 al = *(const float4*)(alpha + p0 + pq);
    const float4 ht = *(const float4*)(hits + hbase + pq);
    float4 o;
    o.x = li.x + (d.x - (ht.x > 0.0f ? mn : 0.0f)) * al.x * GAMMA_C;
    o.y = li.y + (d.y - (ht.y > 0.0f ? mn : 0.0f)) * al.y * GAMMA_C;
    o.z = li.z + (d.z - (ht.z > 0.0f ? mn : 0.0f)) * al.z * GAMMA_C;
    o.w = li.w + (d.w - (ht.w > 0.0f ? mn : 0.0f)) * al.w * GAMMA_C;
    *(float4*)(out + cbase + pq) = o;
  }
}

// ---------------------------------------------------------------------------
extern "C" void kernel_launch(void* const* d_in, const int* in_sizes, int n_in,
                              void* d_out, int out_size, void* d_ws, size_t ws_size,
                              hipStream_t stream)
{
  const float* lidar  = (const float*)d_in[0];
  const float* tokens = (const float*)d_in[1];
  const float* gate   = (const float*)d_in[2];
  const float* alpha  = (const float*)d_in[3];
  const float* q_w    = (const float*)d_in[4];
  const float* q_b    = (const float*)d_in[5];
  const float* k_w    = (const float*)d_in[6];
  const float* v_w    = (const float*)d_in[7];
  const float* out_w  = (const float*)d_in[8];
  const int*   cidx   = (const int*)d_in[9];
  float* out = (float*)d_out;

  char* W = (char*)d_ws;
  // kv_bf [80000][256] bf16
  unsigned short* kv_bf = (unsigned short*)(W + 0);                 // 40,960,000
  // delta [B][HW][128] f32 (66,355,200). Until its memset this region also
  // hosts lidar_t (at +20,480,000 within; 33,177,600) — dead before memset.
  float* delta = (float*)(W + 61440000);
  unsigned short* lidar_t = (unsigned short*)(W + 81920000);
  float* logits   = (float*)(W + 127795200);   // 1,280,000
  int*   pix_ws   = (int*)(W + 129075200);     //   320,000
  float* hits     = (float*)(W + 129395200);   //   518,400
  float* mean_raw = (float*)(W + 129913600);   //     2,048
  float* cnt      = (float*)(W + 129915648);   //        64
  unsigned short* kvw_bf = (unsigned short*)(W + 129915712);  // 131,072
  unsigned short* qw_bf  = (unsigned short*)(W + 130046784);  //  32,768
  unsigned short* ow_bf  = (unsigned short*)(W + 130079552);  //  32,768
  float* pm     = (float*)(W + 130112320);     // 512
  float* ps     = (float*)(W + 130112832);     // 512
  float* smM    = (float*)(W + 130113344);     // 64
  float* smSinv = (float*)(W + 130113408);     // 64

  hipMemsetAsync(hits, 0, (size_t)BB * HWHW * sizeof(float), stream);
  hipMemsetAsync(mean_raw, 0, 2048 + 64, stream);

  k_prep_pix<<<dim3(409), 256, 0, stream>>>(k_w, v_w, q_w, out_w, kvw_bf,
                                            qw_bf, ow_bf, cidx, pix_ws, hits);
  k_tr2<<<dim3(127, BB, 2), 256, 0, stream>>>(lidar, lidar_t);
  // kv projection: [80000,256] x [256,256]^T   (nblk 0 = K rows, 1 = V rows)
  k_gemm<4, 256, 0, 0, 256><<<dim3(625, 2), 256, 0, stream>>>(
      tokens, nullptr, kvw_bf, nullptr, kv_bf, nullptr, nullptr, nullptr,
      nullptr, nullptr, nullptr, nullptr, nullptr);
  // q projection (rows gathered from lidar_t) -> per-head logits directly
  k_gemm<2, 128, 2, 2, 128><<<dim3(625, 1), 256, 0, stream>>>(
      nullptr, lidar_t, qw_bf, q_b, nullptr, pix_ws, logits, kv_bf,
      nullptr, nullptr, nullptr, nullptr, nullptr);
  // lidar_t dead from here
  hipMemsetAsync(delta, 0, (size_t)BB * HWHW * 128 * sizeof(float), stream);
  k_smpart<<<dim3(8, BB * NHEADS), 256, 0, stream>>>(logits, pm, ps);
  k_cntfix<<<dim3(BB), 256, 0, stream>>>(hits, cnt, pm, ps, smM, smSinv);
  // out projection with fused attention-weighted V + scatter + mean accum
  k_gemm<2, 128, 3, 1, 128><<<dim3(625, 1), 256, 0, stream>>>(
      nullptr, nullptr, ow_bf, nullptr, nullptr, pix_ws, delta, kv_bf,
      mean_raw, smM, smSinv, gate, logits);
  k_final<<<dim3(405, BB), 512, 0, stream>>>(lidar, alpha, hits, mean_raw, cnt,
                                             delta, out);
}

// Round 9
// 226.672 us; speedup vs baseline: 1.2135x; 1.0367x over previous
//
#include <hip/hip_runtime.h>

#define BB 4
#define CC 128
#define HH 180
#define WWW 180
#define HWHW (HH*WWW)       // 32400
#define CCAMD 256
#define NHEADS 4
#define HDD 128
#define NT 20000
#define MTOT 80000          // B*N, = 625 * 128 exactly
#define GAMMA_C 0.08f
#define EPS_C 1e-6f
#define SCALE_C 0.17677669529663687f  // 1/sqrt(32)

typedef short bf16x8 __attribute__((ext_vector_type(8)));
typedef float f32x4 __attribute__((ext_vector_type(4)));

typedef __attribute__((address_space(1))) const unsigned int GU;
typedef __attribute__((address_space(3))) unsigned int LU;

static __device__ __forceinline__ void gll16(const void* g, void* l) {
  __builtin_amdgcn_global_load_lds((GU*)g, (LU*)l, 16, 0, 0);
}

static __device__ __forceinline__ unsigned short f2bf(float x) {
  unsigned int b = __float_as_uint(x);
  unsigned int r = (b + 0x7fffu + ((b >> 16) & 1u)) >> 16;
  return (unsigned short)r;
}
static __device__ __forceinline__ float b2f(unsigned short u) {
  return __uint_as_float(((unsigned int)u) << 16);
}

static __device__ __forceinline__ float warpMax(float v) {
#pragma unroll
  for (int o = 32; o >= 1; o >>= 1) v = fmaxf(v, __shfl_xor(v, o));
  return v;
}
static __device__ __forceinline__ float warpSum(float v) {
#pragma unroll
  for (int o = 32; o >= 1; o >>= 1) v += __shfl_xor(v, o);
  return v;
}

// ---------------------------------------------------------------------------
// k_prep_pix: blocks 0..95: weight f32->bf16; blocks 96..408: pixel indices.
// ---------------------------------------------------------------------------
__global__ __launch_bounds__(256) void k_prep_pix(
    const float* __restrict__ kw, const float* __restrict__ vw,
    const float* __restrict__ qw, const float* __restrict__ ow,
    unsigned short* __restrict__ kvw, unsigned short* __restrict__ qwb,
    unsigned short* __restrict__ owb, const int* __restrict__ cidx,
    int* __restrict__ pix_ws, float* __restrict__ hits)
{
  if (blockIdx.x < 96) {
    const int t = blockIdx.x * 256 + threadIdx.x;  // one float4 per thread
    float4 f;
    unsigned short* dst;
    if (t < 16384) {           // kv: 65536 elems
      f = (t < 8192) ? ((const float4*)kw)[t] : ((const float4*)vw)[t - 8192];
      dst = kvw + (size_t)t * 4;
    } else if (t < 20480) {    // q: 16384 elems
      const int i = t - 16384;
      f = ((const float4*)qw)[i];
      dst = qwb + (size_t)i * 4;
    } else {                   // out: 16384 elems
      const int i = t - 20480;
      f = ((const float4*)ow)[i];
      dst = owb + (size_t)i * 4;
    }
    ushort4 u;
    u.x = f2bf(f.x); u.y = f2bf(f.y); u.z = f2bf(f.z); u.w = f2bf(f.w);
    *(ushort4*)dst = u;
  } else {
    const int t = (blockIdx.x - 96) * 256 + threadIdx.x;
    if (t >= MTOT) return;
    const int2 ij = *(const int2*)(cidx + (size_t)t * 2);
    int ii = ij.x; ii = ii < 0 ? 0 : (ii > HH - 1 ? HH - 1 : ii);
    int jj = ij.y; jj = jj < 0 ? 0 : (jj > WWW - 1 ? WWW - 1 : jj);
    const int pix = ii * WWW + jj;
    pix_ws[t] = pix;
    atomicAdd(hits + (size_t)(t / NT) * HWHW + pix, 1.0f);
  }
}

// ---------------------------------------------------------------------------
// k_tr2: lidar_t[b][p][c] (bf16) = lidar[b][c][p].
// ---------------------------------------------------------------------------
__global__ __launch_bounds__(256) void k_tr2(
    const float* __restrict__ lidar, unsigned short* __restrict__ lidar_t)
{
  const int b = blockIdx.y;
  const int p = blockIdx.x * 256 + threadIdx.x;
  if (p >= HWHW) return;
  const int z = blockIdx.z;  // channel half
  const float* src = lidar + ((size_t)b * CC + z * 64) * HWHW + p;
  unsigned short* dst = lidar_t + ((size_t)b * HWHW + p) * 128 + z * 64;
#pragma unroll
  for (int c8 = 0; c8 < 8; ++c8) {
    bf16x8 v;
#pragma unroll
    for (int e = 0; e < 8; ++e)
      v[e] = (short)f2bf(src[(size_t)(c8 * 8 + e) * HWHW]);
    ((bf16x8*)dst)[c8] = v;
  }
}

// ---------------------------------------------------------------------------
// k_zero: zero only HIT delta rows (idempotent concurrent zero-writes).
// 32 lanes per token cover one 512B row. Replaces the 66MB delta memset.
// ---------------------------------------------------------------------------
__global__ __launch_bounds__(256) void k_zero(
    const int* __restrict__ pix_ws, float* __restrict__ delta)
{
  const int t = blockIdx.x * 256 + threadIdx.x;
  const int ng = t >> 5, l32 = t & 31;
  const int b = ng / NT;
  const int pix = pix_ws[ng];
  *(float4*)(delta + ((size_t)b * HWHW + pix) * 128 + l32 * 4) =
      make_float4(0.0f, 0.0f, 0.0f, 0.0f);
}

// ---------------------------------------------------------------------------
// k_gemm: C[M=80000, NOUT] = A[M,K] * W[NOUT,K]^T   (bf16 MFMA 16x16x32)
// BM=BN=128, BK=64, 8 waves (2 wm x 4 wn), each wave 64x32 (acc[4][2]).
// DOUBLE-BUFFERED 2-phase pipeline; reg-staged A modes use the T14 split.
// AMODE 0: A f32 reg-staged+cvt. AMODE 2: A bf16 rows gathered via pixw.
// AMODE 3: A = V-half of kvb * softmax(logit)*gate (reg-staged).
// LDS XOR-swizzled on the source side; matching swizzle on ds_read.
// EPI 0: store bf16 rows. EPI 1: atomic f32 scatter into delta + column sums
// -> meanr. EPI 2: per-head logits vs K-half of kvb (wave wn == head).
// ---------------------------------------------------------------------------
template<int KSTEPS, int KW, int AMODE, int EPI, int NOUT>
__global__ __launch_bounds__(512) void k_gemm(
    const float* __restrict__ Af32, const unsigned short* __restrict__ Abf,
    const unsigned short* __restrict__ Bw, const float* __restrict__ bias,
    unsigned short* __restrict__ Dbf, const int* __restrict__ pixw,
    float* __restrict__ aux,            // EPI1: delta; EPI2: logits out
    const unsigned short* __restrict__ kvb, float* __restrict__ meanr,
    const float* __restrict__ smMp, const float* __restrict__ smSinvp,
    const float* __restrict__ gatep, const float* __restrict__ logp)
{
  __shared__ unsigned short lds[2][16384];  // per buf: A [0,8192), B [8192,16384)
  const int tid = threadIdx.x;
  const int lane = tid & 63, wave = tid >> 6;       // 8 waves
  const int wm = wave >> 2, wn = wave & 3;          // 2 x 4
  const int mblk = blockIdx.x, nblk = blockIdx.y;
  const int l16 = lane & 15, kg = lane >> 4;

  const int g3 = lane >> 3;        // row within 8-row group (== lds_row & 7)
  const int c8l = lane & 7;
  const int grow0 = wave * 8 + g3;                  // 8 waves x 8 = 64 rows/chunk
  const int gcol_lin = c8l * 8;
  const int gcol_swz = (c8l ^ g3) * 8;

  f32x4 acc[4][2];
#pragma unroll
  for (int i = 0; i < 4; ++i)
#pragma unroll
    for (int j = 0; j < 2; ++j) acc[i][j] = (f32x4)0.0f;

  // per-w2 A pointers / params (2 chunks of 64 rows)
  const float* a32p[2];
  const unsigned short* arow[2];
  const unsigned short* vrow[2];
  float ga4[2];
  int lbase[2], rb4[2];
  if constexpr (AMODE == 0) {
#pragma unroll
    for (int w2 = 0; w2 < 2; ++w2)
      a32p[w2] = Af32 + (size_t)(mblk * 128 + w2 * 64 + grow0) * KW + gcol_lin;
  } else if constexpr (AMODE == 2) {
#pragma unroll
    for (int w2 = 0; w2 < 2; ++w2) {
      const int r = mblk * 128 + w2 * 64 + grow0;
      const int bb = r / NT;
      const int pix = pixw[r];
      arow[w2] = Abf + ((size_t)bb * HWHW + pix) * 128 + gcol_swz;
    }
  } else if constexpr (AMODE == 3) {
#pragma unroll
    for (int w2 = 0; w2 < 2; ++w2) {
      const int r = mblk * 128 + w2 * 64 + grow0;
      const int bb = r / NT, n = r - bb * NT;
      vrow[w2] = kvb + (size_t)r * 256 + 128 + gcol_lin;
      ga4[w2] = gatep[(size_t)bb * NT + n];
      lbase[w2] = bb * NHEADS * NT + n;
      rb4[w2] = bb;
    }
  }

  bf16x8 areg[2];  // in-flight A fragments for reg-staged modes

  auto loadA = [&](int kt) {
    if constexpr (AMODE == 0) {
#pragma unroll
      for (int w2 = 0; w2 < 2; ++w2) {
        const float* g = a32p[w2] + kt * 64;
        const float4 f0 = *(const float4*)g;
        const float4 f1 = *(const float4*)(g + 4);
        bf16x8 v;
        v[0] = (short)f2bf(f0.x); v[1] = (short)f2bf(f0.y);
        v[2] = (short)f2bf(f0.z); v[3] = (short)f2bf(f0.w);
        v[4] = (short)f2bf(f1.x); v[5] = (short)f2bf(f1.y);
        v[6] = (short)f2bf(f1.z); v[7] = (short)f2bf(f1.w);
        areg[w2] = v;
      }
    } else if constexpr (AMODE == 3) {
      const int h = kt * 2 + (c8l >> 2);
#pragma unroll
      for (int w2 = 0; w2 < 2; ++w2) {
        const int bh = rb4[w2] * NHEADS + h;
        const float coef =
            __expf(logp[lbase[w2] + h * NT] - smMp[bh]) * smSinvp[bh] * ga4[w2];
        const bf16x8 v = *(const bf16x8*)(vrow[w2] + kt * 64);
        bf16x8 o;
#pragma unroll
        for (int e = 0; e < 8; ++e)
          o[e] = (short)f2bf(b2f((unsigned short)v[e]) * coef);
        areg[w2] = o;
      }
    }
  };
  auto writeA = [&](int nb) {
#pragma unroll
    for (int w2 = 0; w2 < 2; ++w2)
      *(bf16x8*)&lds[nb][w2 * 4096 + wave * 512 + g3 * 64 + gcol_swz] = areg[w2];
  };
  auto stageAg = [&](int kt, int nb) {  // AMODE 2: gll16 direct (source pre-swz)
    if constexpr (AMODE == 2) {
#pragma unroll
      for (int w2 = 0; w2 < 2; ++w2)
        gll16(arow[w2] + kt * 64, &lds[nb][w2 * 4096 + wave * 512]);
    }
  };
  auto stageB = [&](int kt, int nb) {
#pragma unroll
    for (int w2 = 0; w2 < 2; ++w2) {
      const unsigned short* g =
          Bw + (size_t)(nblk * 128 + w2 * 64 + grow0) * KW + kt * 64 + gcol_swz;
      gll16(g, &lds[nb][8192 + w2 * 4096 + wave * 512]);
    }
  };
  auto compute = [&](int cb) {
#pragma unroll
    for (int ks = 0; ks < 2; ++ks) {
      const int swz = ((ks * 4 + kg) ^ (l16 & 7)) * 8;
      bf16x8 a[4], b[2];
#pragma unroll
      for (int mf = 0; mf < 4; ++mf)
        a[mf] = *(const bf16x8*)&lds[cb][(wm * 64 + mf * 16 + l16) * 64 + swz];
#pragma unroll
      for (int nf = 0; nf < 2; ++nf)
        b[nf] = *(const bf16x8*)&lds[cb][8192 + (wn * 32 + nf * 16 + l16) * 64 + swz];
#pragma unroll
      for (int mf = 0; mf < 4; ++mf)
#pragma unroll
        for (int nf = 0; nf < 2; ++nf)
          acc[mf][nf] =
              __builtin_amdgcn_mfma_f32_16x16x32_bf16(a[mf], b[nf], acc[mf][nf], 0, 0, 0);
    }
  };

  // ---- prologue: stage tile 0 into buf 0 ----
  if constexpr (AMODE == 0 || AMODE == 3) {
    loadA(0);
    writeA(0);
  } else {
    stageAg(0, 0);
  }
  stageB(0, 0);
  __syncthreads();

  // ---- 2-phase pipelined K-loop ----
  int cur = 0;
  for (int kt = 0; kt < KSTEPS; ++kt) {
    if (kt + 1 < KSTEPS) {
      if constexpr (AMODE == 0 || AMODE == 3) loadA(kt + 1);
      else stageAg(kt + 1, cur ^ 1);
      stageB(kt + 1, cur ^ 1);
    }
    compute(cur);
    if (kt + 1 < KSTEPS) {
      if constexpr (AMODE == 0 || AMODE == 3) writeA(cur ^ 1);
    }
    __syncthreads();
    cur ^= 1;
  }

  float* scratch = (float*)&lds[0][0];  // free after final barrier

  // ---- epilogue ----
  if constexpr (EPI == 0) {
#pragma unroll
    for (int mf = 0; mf < 4; ++mf) {
#pragma unroll
      for (int j = 0; j < 4; ++j) {
        const int row = mblk * 128 + wm * 64 + mf * 16 + kg * 4 + j;
        unsigned short* dr = Dbf + (size_t)row * NOUT + nblk * 128 + wn * 32 + l16;
#pragma unroll
        for (int nf = 0; nf < 2; ++nf)
          dr[nf * 16] = f2bf(acc[mf][nf][j]);
      }
    }
  } else if constexpr (EPI == 1) {
    // scatter + block column sums
    if (tid < 256) scratch[tid] = 0.0f;
    __syncthreads();
    const int b0 = (mblk * 128) / NT;
#pragma unroll
    for (int mf = 0; mf < 4; ++mf) {
      const int baser = mblk * 128 + wm * 64 + mf * 16 + kg * 4;
      const int bb = baser / NT;          // uniform over j (NT % 4 == 0)
      const int bsel = (bb != b0) ? 1 : 0;
      float s[2] = {0.0f, 0.0f};
#pragma unroll
      for (int j = 0; j < 4; ++j) {
        const int row = baser + j;
        const int pix = pixw[row];
        float* dr = aux + ((size_t)bb * HWHW + pix) * 128 + wn * 32 + l16;
#pragma unroll
        for (int nf = 0; nf < 2; ++nf) {
          atomicAdd(dr + nf * 16, acc[mf][nf][j]);
          s[nf] += acc[mf][nf][j];
        }
      }
#pragma unroll
      for (int nf = 0; nf < 2; ++nf)
        atomicAdd(&scratch[bsel * 128 + wn * 32 + nf * 16 + l16], s[nf]);
    }
    __syncthreads();
    const int b1 = (mblk * 128 + 127) / NT;
    if (tid < 128) atomicAdd(meanr + (size_t)b0 * 128 + tid, scratch[tid]);
    else if (tid < 256 && b1 != b0)
      atomicAdd(meanr + (size_t)b1 * 128 + (tid - 128), scratch[tid]);
  } else {
    // EPI 2: logits. Wave's 32-col span = head wn. Reduce over l16 group.
    float bv[2];
#pragma unroll
    for (int nf = 0; nf < 2; ++nf)
      bv[nf] = bias[wn * 32 + nf * 16 + l16];
#pragma unroll
    for (int mf = 0; mf < 4; ++mf) {
#pragma unroll
      for (int j = 0; j < 4; ++j) {
        const int rl = wm * 64 + mf * 16 + kg * 4 + j;
        const int row = mblk * 128 + rl;
        const unsigned short* kr = kvb + (size_t)row * 256 + wn * 32 + l16;
        float s = (acc[mf][0][j] + bv[0]) * b2f(kr[0]) +
                  (acc[mf][1][j] + bv[1]) * b2f(kr[16]);
        s += __shfl_xor(s, 8, 16); s += __shfl_xor(s, 4, 16);
        s += __shfl_xor(s, 2, 16); s += __shfl_xor(s, 1, 16);
        if (l16 == 0) scratch[rl * 4 + wn] = s;
      }
    }
    __syncthreads();
    if (tid < 128) {
      const int row = mblk * 128 + tid;
      const int bb = row / NT, n = row - bb * NT;
#pragma unroll
      for (int h = 0; h < 4; ++h)
        aux[((size_t)bb * NHEADS + h) * NT + n] = scratch[tid * 4 + h] * SCALE_C;
    }
  }
}

// ---------------------------------------------------------------------------
// k_smpart: per-(bh, chunk) partial max & sum-exp.  NT = 8 * 2500.
// ---------------------------------------------------------------------------
__global__ __launch_bounds__(256) void k_smpart(
    const float* __restrict__ logits, float* __restrict__ pm,
    float* __restrict__ ps)
{
  const int ch = blockIdx.x, bh = blockIdx.y;
  const float* L = logits + (size_t)bh * NT + ch * 2500;
  const int tid = threadIdx.x;
  __shared__ float sred[4];

  float m = -INFINITY;
  for (int i = tid; i < 2500; i += 256) m = fmaxf(m, L[i]);
  m = warpMax(m);
  if ((tid & 63) == 0) sred[tid >> 6] = m;
  __syncthreads();
  m = fmaxf(fmaxf(sred[0], sred[1]), fmaxf(sred[2], sred[3]));

  float s = 0.0f;
  for (int i = tid; i < 2500; i += 256) s += __expf(L[i] - m);
  s = warpSum(s);
  __syncthreads();
  if ((tid & 63) == 0) sred[tid >> 6] = s;
  __syncthreads();
  if (tid == 0) {
    pm[bh * 8 + ch] = m;
    ps[bh * 8 + ch] = sred[0] + sred[1] + sred[2] + sred[3];
  }
}

// ---------------------------------------------------------------------------
// k_cntfix: block b: cnt[b] = #hit pixels. Block 0 also combines softmax
// partials -> smM, smSinv.
// ---------------------------------------------------------------------------
__global__ __launch_bounds__(256) void k_cntfix(
    const float* __restrict__ hits, float* __restrict__ cnt,
    const float* __restrict__ pm, const float* __restrict__ ps,
    float* __restrict__ smM, float* __restrict__ smSinv)
{
  const int b = blockIdx.x;
  const int tid = threadIdx.x;
  float s = 0.0f;
  for (int i = tid; i < HWHW; i += 256)
    s += (hits[(size_t)b * HWHW + i] > 0.0f) ? 1.0f : 0.0f;
  s = warpSum(s);
  __shared__ float sred[4];
  if ((tid & 63) == 0) sred[tid >> 6] = s;
  __syncthreads();
  if (tid == 0) cnt[b] = sred[0] + sred[1] + sred[2] + sred[3];
  if (b == 0 && tid < BB * NHEADS) {
    float M = -INFINITY;
#pragma unroll
    for (int c = 0; c < 8; ++c) M = fmaxf(M, pm[tid * 8 + c]);
    float S = 0.0f;
#pragma unroll
    for (int c = 0; c < 8; ++c) S += ps[tid * 8 + c] * __expf(pm[tid * 8 + c] - M);
    smM[tid] = M;
    smSinv[tid] = 1.0f / S;
  }
}

// ---------------------------------------------------------------------------
// k_final: out[b][c][hw] = lidar + (delta[b][hw][c] - mean*mask)*alpha*gamma
// 80px x 128ch tiles, 512 threads; hits-gated delta reads; XOR-swizzled LDS.
// ---------------------------------------------------------------------------
__global__ __launch_bounds__(512) void k_final(
    const float* __restrict__ lidar, const float* __restrict__ alpha,
    const float* __restrict__ hits, const float* __restrict__ mean_raw,
    const float* __restrict__ cnt, const float* __restrict__ delta,
    float* __restrict__ out)
{
  __shared__ float tile[80 * 136];
  const int b = blockIdx.y;
  const int p0 = blockIdx.x * 80;
  const int t = threadIdx.x;
  const float4* dsrc = (const float4*)(delta + ((size_t)b * HWHW + p0) * 128);
  const float* hrow = hits + (size_t)b * HWHW + p0;
#pragma unroll
  for (int i = 0; i < 5; ++i) {
    const int idx4 = i * 512 + t;         // 2560 float4 = 80px * 32
    const int p = idx4 >> 5, c4 = idx4 & 31;
    float4 f = make_float4(0.0f, 0.0f, 0.0f, 0.0f);
    if (hrow[p] > 0.0f) f = dsrc[idx4];
    *(float4*)&tile[p * 136 + ((c4 ^ (p & 7)) << 2)] = f;
  }
  __syncthreads();
  const int c = t >> 2, sub = t & 3;
  const int cq = c >> 2, cr = c & 3;
  const float mn = mean_raw[b * 128 + c] / (cnt[b] + EPS_C);
  const size_t cbase = ((size_t)b * CC + c) * HWHW + p0;
  const size_t hbase = (size_t)b * HWHW + p0;
#pragma unroll
  for (int j = 0; j < 5; ++j) {
    const int pq = j * 16 + sub * 4;
    float4 d;
    d.x = tile[(pq + 0) * 136 + (((cq ^ ((pq + 0) & 7)) << 2) | cr)];
    d.y = tile[(pq + 1) * 136 + (((cq ^ ((pq + 1) & 7)) << 2) | cr)];
    d.z = tile[(pq + 2) * 136 + (((cq ^ ((pq + 2) & 7)) << 2) | cr)];
    d.w = tile[(pq + 3) * 136 + (((cq ^ ((pq + 3) & 7)) << 2) | cr)];
    const float4 li = *(const float4*)(lidar + cbase + pq);
    const float4 al = *(const float4*)(alpha + p0 + pq);
    const float4 ht = *(const float4*)(hits + hbase + pq);
    float4 o;
    o.x = li.x + (d.x - (ht.x > 0.0f ? mn : 0.0f)) * al.x * GAMMA_C;
    o.y = li.y + (d.y - (ht.y > 0.0f ? mn : 0.0f)) * al.y * GAMMA_C;
    o.z = li.z + (d.z - (ht.z > 0.0f ? mn : 0.0f)) * al.z * GAMMA_C;
    o.w = li.w + (d.w - (ht.w > 0.0f ? mn : 0.0f)) * al.w * GAMMA_C;
    *(float4*)(out + cbase + pq) = o;
  }
}

// ---------------------------------------------------------------------------
extern "C" void kernel_launch(void* const* d_in, const int* in_sizes, int n_in,
                              void* d_out, int out_size, void* d_ws, size_t ws_size,
                              hipStream_t stream)
{
  const float* lidar  = (const float*)d_in[0];
  const float* tokens = (const float*)d_in[1];
  const float* gate   = (const float*)d_in[2];
  const float* alpha  = (const float*)d_in[3];
  const float* q_w    = (const float*)d_in[4];
  const float* q_b    = (const float*)d_in[5];
  const float* k_w    = (const float*)d_in[6];
  const float* v_w    = (const float*)d_in[7];
  const float* out_w  = (const float*)d_in[8];
  const int*   cidx   = (const int*)d_in[9];
  float* out = (float*)d_out;

  char* W = (char*)d_ws;
  // kv_bf [80000][256] bf16
  unsigned short* kv_bf = (unsigned short*)(W + 0);                 // 40,960,000
  // delta [B][HW][128] f32 (66,355,200). Until k_zero this region also
  // hosts lidar_t (at +20,480,000 within; 33,177,600) — dead before k_zero.
  float* delta = (float*)(W + 61440000);
  unsigned short* lidar_t = (unsigned short*)(W + 81920000);
  float* logits   = (float*)(W + 127795200);   // 1,280,000
  int*   pix_ws   = (int*)(W + 129075200);     //   320,000
  float* hits     = (float*)(W + 129395200);   //   518,400
  float* mean_raw = (float*)(W + 129913600);   //     2,048
  float* cnt      = (float*)(W + 129915648);   //        64
  unsigned short* kvw_bf = (unsigned short*)(W + 129915712);  // 131,072
  unsigned short* qw_bf  = (unsigned short*)(W + 130046784);  //  32,768
  unsigned short* ow_bf  = (unsigned short*)(W + 130079552);  //  32,768
  float* pm     = (float*)(W + 130112320);     // 512
  float* ps     = (float*)(W + 130112832);     // 512
  float* smM    = (float*)(W + 130113344);     // 64
  float* smSinv = (float*)(W + 130113408);     // 64

  hipMemsetAsync(hits, 0, (size_t)BB * HWHW * sizeof(float), stream);
  hipMemsetAsync(mean_raw, 0, 2048 + 64, stream);

  k_prep_pix<<<dim3(409), 256, 0, stream>>>(k_w, v_w, q_w, out_w, kvw_bf,
                                            qw_bf, ow_bf, cidx, pix_ws, hits);
  k_tr2<<<dim3(127, BB, 2), 256, 0, stream>>>(lidar, lidar_t);
  // kv projection: [80000,256] x [256,256]^T   (nblk 0 = K rows, 1 = V rows)
  k_gemm<4, 256, 0, 0, 256><<<dim3(625, 2), 512, 0, stream>>>(
      tokens, nullptr, kvw_bf, nullptr, kv_bf, nullptr, nullptr, nullptr,
      nullptr, nullptr, nullptr, nullptr, nullptr);
  // q projection (rows gathered from lidar_t) -> per-head logits directly
  k_gemm<2, 128, 2, 2, 128><<<dim3(625, 1), 512, 0, stream>>>(
      nullptr, lidar_t, qw_bf, q_b, nullptr, pix_ws, logits, kv_bf,
      nullptr, nullptr, nullptr, nullptr, nullptr);
  // lidar_t dead from here: zero only hit delta rows (replaces 66MB memset)
  k_zero<<<dim3(10000), 256, 0, stream>>>(pix_ws, delta);
  k_smpart<<<dim3(8, BB * NHEADS), 256, 0, stream>>>(logits, pm, ps);
  k_cntfix<<<dim3(BB), 256, 0, stream>>>(hits, cnt, pm, ps, smM, smSinv);
  // out projection with fused attention-weighted V + scatter + mean accum
  k_gemm<2, 128, 3, 1, 128><<<dim3(625, 1), 512, 0, stream>>>(
      nullptr, nullptr, ow_bf, nullptr, nullptr, pix_ws, delta, kv_bf,
      mean_raw, smM, smSinv, gate, logits);
  k_final<<<dim3(405, BB), 512, 0, stream>>>(lidar, alpha, hits, mean_raw, cnt,
                                             delta, out);
}